// Round 5
// baseline (99.024 us; speedup 1.0000x reference)
//
#include <hip/hip_runtime.h>

// TorchVQC: 8-qubit statevector, B=16384, D=256, fp32 complex.
// R12 = R11 with dpp ctrl made a template constant (builtin requires a
// frontend-constant integer; runtime param fails even when force-inlined).
// Content unchanged from R10 plan:
//  (a) gate chain 100% LDS-free: all cross-lane xors are DPP
//      (xor4=quad1B*halfmirror, xor6=quadB1*halfmirror, xorC=quad1B*mirror),
//      FUSED coefficient broadcasts (32 ds_swizzle) prefetched into arrays
//      right after the F-build, ~1000cy before first use -> latency hidden.
//  (b) DIAGNOSTIC: one discarded repeat of the 16-gate core after the
//      store (asm-fenced against CSE/DCE) to push vqc above the 40us harness
//      fills so its rocprof counters appear in the top-5 table. Strip next.
// Layout: 4 batch elements per wave (16 lanes each), 16 amplitudes per lane.
// Stored index s = (j<<4) | lane16. CNOTs folded via GF(2) relabeling
// (v/u tables verified R2-R4); R7 SU(2) sign-folding kept.

using f2 = __attribute__((ext_vector_type(2))) float;  // (re, im)

__device__ __forceinline__ f2 cmul2(f2 w, f2 z) {
    f2 r;
    r.x = w.x * z.x - w.y * z.y;
    r.y = w.x * z.y + w.y * z.x;
    return r;
}
__device__ __forceinline__ f2 cmadd(f2 acc, f2 w, f2 z) {
    acc.x += w.x * z.x - w.y * z.y;
    acc.y += w.x * z.y + w.y * z.x;
    return acc;
}

__device__ __forceinline__ float uxor(float f, unsigned u) {
    return __uint_as_float(__float_as_uint(f) ^ u);
}

template<int CTRL>
__device__ __forceinline__ int dpp1(int x) {
    return __builtin_amdgcn_update_dpp(x, x, CTRL, 0xF, 0xF, false);
}

// cross-lane value of (lane ^ M), M < 16 — ALL DPP (VALU), no LDS pipe.
// quad_perm 0xB1 = xor1, 0x4E = xor2, 0x1B = xor3; 0x128 row_ror:8 = xor8;
// 0x140 row_mirror = xorF; 0x141 row_half_mirror = xor7. Composites:
// xor4 = xor3 . xor7, xor6 = xor1 . xor7, xorC = xor3 . xorF.
template<int M>
__device__ __forceinline__ float xlane(float v) {
    const int x = __float_as_int(v);
    int r;
    if constexpr (M == 1)        r = dpp1<0xB1>(x);
    else if constexpr (M == 2)   r = dpp1<0x4E>(x);
    else if constexpr (M == 3)   r = dpp1<0x1B>(x);
    else if constexpr (M == 8)   r = dpp1<0x128>(x);
    else if constexpr (M == 0xF) r = dpp1<0x140>(x);
    else if constexpr (M == 7)   r = dpp1<0x141>(x);
    else if constexpr (M == 4)   r = dpp1<0x141>(dpp1<0x1B>(x));
    else if constexpr (M == 6)   r = dpp1<0x141>(dpp1<0xB1>(x));
    else if constexpr (M == 0xC) r = dpp1<0x140>(dpp1<0x1B>(x));
    else                         r = __builtin_amdgcn_ds_swizzle(x, (M << 10) | 0x1F);
    return __int_as_float(r);
}
template<int M>
__device__ __forceinline__ f2 xshfl2(f2 v) {
    f2 r; r.x = xlane<M>(v.x); r.y = xlane<M>(v.y); return r;
}

// broadcast lane (group8_base + K) within each group of 8 — K compile-time
template<int K>
__device__ __forceinline__ float bc8(float x) {
    return __int_as_float(__builtin_amdgcn_ds_swizzle(
        __float_as_int(x), (K << 5) | 0x18));
}
// fetch lane (lane & 0x17) | 8  (layer-1 gate params held by lanes 8..15 mod 16)
#define SW117(x) __int_as_float(__builtin_amdgcn_ds_swizzle(__float_as_int(x), 0x117))

// compile-time prefetch of all 8 fused-gate coefficient quads
template<int K>
__device__ __forceinline__ void prefetchK(float (&cf0r)[8], float (&cf0i)[8],
                                          float (&cf1r)[8], float (&cf1i)[8],
                                          float F00x, float F00y,
                                          float F01x, float F01y) {
    cf0r[K] = bc8<K>(F00x); cf0i[K] = bc8<K>(F00y);
    cf1r[K] = bc8<K>(F01x); cf1i[K] = bc8<K>(F01y);
    if constexpr (K < 7)
        prefetchK<K + 1>(cf0r, cf0i, cf1r, cf1i, F00x, F00y, F01x, F01y);
}

// selected encoding-column entry: hi ? (s*cp, s*sp) : (c*cp, -c*sp)
__device__ __forceinline__ f2 enc_sel(float t, float p, bool hi) {
    float s_, c_, sp_, cp_;
    __sincosf(t * 0.5f, &s_, &c_);
    __sincosf(p * 0.5f, &sp_, &cp_);
    const float m = hi ? s_ : c_;
    f2 r; r.x = m * cp_; r.y = hi ? m * sp_ : -m * sp_;
    return r;
}

// SU(2) gate under relabeling (R7 sign-folding).
template<int VREG, int VLANE, int UREG>
__device__ __forceinline__ void gateU(f2 (&s)[16],
                                      float g00r, float giP, float brP, float g01i)
{
    if constexpr (VLANE == 0) {
        constexpr int pivot = VREG & (-VREG);
        #pragma unroll
        for (int j = 0; j < 16; ++j) {
            if ((j & pivot) != 0) continue;
            const int j2 = j ^ VREG;
            const f2 x = s[j], y = s[j2];
            {
                const bool n = (__builtin_popcount(j & UREG) & 1) != 0;
                const float gi = n ? -giP : giP, br = n ? -brP : brP;
                s[j].x = fmaf(-g01i, y.y, fmaf(br, y.x, fmaf(-gi, x.y, g00r * x.x)));
                s[j].y = fmaf( g01i, y.x, fmaf(br, y.y, fmaf( gi, x.x, g00r * x.y)));
            }
            {
                const bool n = (__builtin_popcount(j2 & UREG) & 1) != 0;
                const float gi = n ? -giP : giP, br = n ? -brP : brP;
                s[j2].x = fmaf(-g01i, x.y, fmaf(br, x.x, fmaf(-gi, y.y, g00r * y.x)));
                s[j2].y = fmaf( g01i, x.x, fmaf(br, x.y, fmaf( gi, y.x, g00r * y.y)));
            }
        }
    } else if constexpr (VREG == 0) {
        #pragma unroll
        for (int j = 0; j < 16; ++j) {
            const f2 w = xshfl2<VLANE>(s[j]);
            const f2 x = s[j];
            const bool n = (__builtin_popcount(j & UREG) & 1) != 0;
            const float gi = n ? -giP : giP, br = n ? -brP : brP;
            s[j].x = fmaf(-g01i, w.y, fmaf(br, w.x, fmaf(-gi, x.y, g00r * x.x)));
            s[j].y = fmaf( g01i, w.x, fmaf(br, w.y, fmaf( gi, x.x, g00r * x.y)));
        }
    } else {
        constexpr int pivot = VREG & (-VREG);
        #pragma unroll
        for (int j = 0; j < 16; ++j) {
            if ((j & pivot) != 0) continue;
            const int j2 = j ^ VREG;
            const f2 p1 = xshfl2<VLANE>(s[j2]);
            const f2 p2 = xshfl2<VLANE>(s[j]);
            const f2 x = s[j], y = s[j2];
            {
                const bool n = (__builtin_popcount(j & UREG) & 1) != 0;
                const float gi = n ? -giP : giP, br = n ? -brP : brP;
                s[j].x = fmaf(-g01i, p1.y, fmaf(br, p1.x, fmaf(-gi, x.y, g00r * x.x)));
                s[j].y = fmaf( g01i, p1.x, fmaf(br, p1.y, fmaf( gi, x.x, g00r * x.y)));
            }
            {
                const bool n = (__builtin_popcount(j2 & UREG) & 1) != 0;
                const float gi = n ? -giP : giP, br = n ? -brP : brP;
                s[j2].x = fmaf(-g01i, p2.y, fmaf(br, p2.x, fmaf(-gi, y.y, g00r * y.x)));
                s[j2].y = fmaf( g01i, p2.x, fmaf(br, p2.y, fmaf( gi, y.x, g00r * y.y)));
            }
        }
    }
}

// uniform broadcast from wave lane t (compile-time) -> SGPR
#define RL(x, t) __int_as_float(__builtin_amdgcn_readlane(__float_as_int(x), (t)))

// layer-0 Rot: coefficients wave-uniform, read from lane K's w-gate regs
#define ROT0(K, VR, VL, UR, SL) do {                                       \
    const float g0r = RL(q00r, K), g0i = RL(q00i, K);                      \
    const float g1r = RL(q01r, K), g1i = RL(q01i, K);                      \
    gateU<VR, VL, UR>(s, g0r, uxor(g0i, SL), uxor(g1r, SL), g1i);          \
} while (0)

// fused Renc(K)+Rot(1,K): coefficients prefetched into cf*[K] (DS done long ago)
#define FUSED(K, VR, VL, UR, SL) do {                                      \
    gateU<VR, VL, UR>(s, cf0r[K], uxor(cf0i[K], SL),                       \
                      uxor(cf1r[K], SL), cf1i[K]);                         \
} while (0)

__global__ __launch_bounds__(256, 4) void vqc_kernel(
    const float* __restrict__ theta,   // [B,8]
    const float* __restrict__ phi,     // [B,8]
    const float* __restrict__ jup,     // [B,28]
    const float* __restrict__ w,       // [2,8,3] vqc weights
    float* __restrict__ out,           // [B,8]
    int Btot)
{
    const int gtid   = blockIdx.x * 256 + threadIdx.x;
    const int lane   = threadIdx.x & 63;
    const int lane16 = lane & 15;
    const int bq     = gtid >> 4;                   // one batch per 16 lanes
    const int b      = bq < Btot ? bq : Btot - 1;   // clamp for loads

    // ---- w-gate prep (lane t holds gate t=lane&15; layer0=0..7, layer1=8..15)
    // Rot = RZ(om)RY(th)RZ(ph): g00=c e^{-i(ph+om)/2}, g01=-s e^{+i(ph-om)/2}
    float q00r, q00i, q01r, q01i;
    {
        const int gt = lane & 15;
        const float wph = w[gt*3+0], wth = w[gt*3+1], wom = w[gt*3+2];
        float gc_, gs_, ca_, sa_, cb_, sb_;
        __sincosf(wth * 0.5f, &gs_, &gc_);
        __sincosf(0.5f * (wph + wom), &sa_, &ca_);
        __sincosf(0.5f * (wph - wom), &sb_, &cb_);
        q00r =  gc_*ca_;  q00i = -gc_*sa_;
        q01r = -gs_*cb_;  q01i = -gs_*sb_;
    }

    // per-lane K for the fused-gate build, issue its loads early
    const int Kq = lane & 7;
    const float thK = theta[(size_t)b * 8 + Kq];
    const float phK = phi  [(size_t)b * 8 + Kq];

    float th[8], ph[8];
    {
        const float4* t4 = reinterpret_cast<const float4*>(theta + (size_t)b * 8);
        const float4* p4 = reinterpret_cast<const float4*>(phi   + (size_t)b * 8);
        const float4 a = t4[0], c = t4[1], d = p4[0], e = p4[1];
        th[0]=a.x; th[1]=a.y; th[2]=a.z; th[3]=a.w;
        th[4]=c.x; th[5]=c.y; th[6]=c.z; th[7]=c.w;
        ph[0]=d.x; ph[1]=d.y; ph[2]=d.z; ph[3]=d.w;
        ph[4]=e.x; ph[5]=e.y; ph[6]=e.z; ph[7]=e.w;
    }

    // ---- distributed FUSED-gate build (R8-verified math) ----
    // F = Rot(1,K) . Renc(K); only F00,F01 needed (SU(2)).
    float F00x, F00y, F01x, F01y;
    {
        float c_, s_, cp_, sp_;
        __sincosf(thK * 0.25f, &s_, &c_);
        __sincosf(phK * 0.25f, &sp_, &cp_);
        const f2 R00 = { SW117(q00r), SW117(q00i) };   // layer-1 gate Kq
        const f2 R01 = { SW117(q01r), SW117(q01i) };
        const f2 E00 = { c_*cp_, -c_*sp_}, E10 = { s_*cp_,  s_*sp_};
        const f2 E01 = {-s_*cp_,  s_*sp_}, E11 = { c_*cp_,  c_*sp_};
        const f2 F00 = cmadd(cmul2(R00, E00), R01, E10);
        const f2 F01 = cmadd(cmul2(R00, E01), R01, E11);
        F00x = F00.x; F00y = F00.y; F01x = F01.x; F01y = F01.y;
    }

    // ---- prefetch ALL fused-gate coefficients now (32 ds_swizzle issued
    // back-to-back; consumed ~1000cy later, after init + 8 ROT0 gates) ----
    float cf0r[8], cf0i[8], cf1r[8], cf1i[8];
    prefetchK<0>(cf0r, cf0i, cf1r, cf1i, F00x, F00y, F01x, F01y);

    // lane-parity sign words (bit31) for ULANE masks used by the gate table
    const unsigned s8 = (unsigned)(lane16 & 8) << 28;
    const unsigned s4 = (unsigned)(lane16 & 4) << 29;
    const unsigned s2 = (unsigned)(lane16 & 2) << 30;
    const unsigned s1 = (unsigned)(lane16 & 1) << 31;
    const unsigned sC = s8 ^ s4;
    const unsigned sE = sC ^ s2;
    const unsigned sF = sE ^ s1;

    // ---- lane-side encoding product over qubits 4..7 ----
    f2 P = enc_sel(th[4], ph[4], (lane16 & 8) != 0);
    P = cmul2(P, enc_sel(th[5], ph[5], (lane16 & 4) != 0));
    P = cmul2(P, enc_sel(th[6], ph[6], (lane16 & 2) != 0));
    P = cmul2(P, enc_sel(th[7], ph[7], (lane16 & 1) != 0));

    // ---- register-side partial products m01 (qubits 0,1), m23 (qubits 2,3) ----
    f2 m01[4], m23[4];
    {
        float s0, c0, sp0, cp0, s1_, c1_, sp1, cp1;
        __sincosf(th[0]*0.5f, &s0, &c0); __sincosf(ph[0]*0.5f, &sp0, &cp0);
        __sincosf(th[1]*0.5f, &s1_, &c1_); __sincosf(ph[1]*0.5f, &sp1, &cp1);
        const f2 A0={c0*cp0,-c0*sp0}, A1={s0*cp0,s0*sp0};
        const f2 B0={c1_*cp1,-c1_*sp1}, B1={s1_*cp1,s1_*sp1};
        #pragma unroll
        for (int a = 0; a < 4; ++a)
            m01[a] = cmul2((a & 2) ? A1 : A0, (a & 1) ? B1 : B0);
        __sincosf(th[2]*0.5f, &s0, &c0); __sincosf(ph[2]*0.5f, &sp0, &cp0);
        __sincosf(th[3]*0.5f, &s1_, &c1_); __sincosf(ph[3]*0.5f, &sp1, &cp1);
        const f2 C0={c0*cp0,-c0*sp0}, C1={s0*cp0,s0*sp0};
        const f2 D0={c1_*cp1,-c1_*sp1}, D1={s1_*cp1,s1_*sp1};
        #pragma unroll
        for (int a = 0; a < 4; ++a)
            m23[a] = cmul2((a & 2) ? C1 : C0, (a & 1) ? D1 : D0);
    }

    // ---- IsingZZ reduction: J[28] -> c01..c23, Q0..Q3, LL ----
    float c01, c02, c03, c12, c13, c23, Q0, Q1, Q2, Q3, LL;
    {
        const float4* J4 = reinterpret_cast<const float4*>(jup + (size_t)b * 28);
        const float z4 = (lane16 & 8) ? -1.f : 1.f;
        const float z5 = (lane16 & 4) ? -1.f : 1.f;
        const float z6 = (lane16 & 2) ? -1.f : 1.f;
        const float z7 = (lane16 & 1) ? -1.f : 1.f;
        const float4 x0 = J4[0], x1 = J4[1], x2 = J4[2], x3 = J4[3];
        const float4 x4 = J4[4], x5 = J4[5], x6 = J4[6];
        c01 = x0.x; c02 = x0.y; c03 = x0.z;
        Q0  = x0.w*z4 + x1.x*z5 + x1.y*z6 + x1.z*z7;
        c12 = x1.w; c13 = x2.x;
        Q1  = x2.y*z4 + x2.z*z5 + x2.w*z6 + x3.x*z7;
        c23 = x3.y;
        Q2  = x3.z*z4 + x3.w*z5 + x4.x*z6 + x4.y*z7;
        Q3  = x4.z*z4 + x4.w*z5 + x5.x*z6 + x5.y*z7;
        LL  = x5.z*(z4*z5) + x5.w*(z4*z6) + x6.x*(z4*z7)
            + x6.y*(z5*z6) + x6.z*(z5*z7) + x6.w*(z6*z7);
    }

    // ---- init amplitudes: product state x Ising phase ----
    f2 s[16];
    constexpr float HPI = 1.5707963267948966f;
    #pragma unroll
    for (int j = 0; j < 16; ++j) {
        f2 u = cmul2(cmul2(m01[j >> 2], m23[j & 3]), P);
        float S = LL;
        S += ((__builtin_popcount(j & 0xC) & 1) ? -c01 : c01);
        S += ((__builtin_popcount(j & 0xA) & 1) ? -c02 : c02);
        S += ((__builtin_popcount(j & 0x9) & 1) ? -c03 : c03);
        S += ((__builtin_popcount(j & 0x6) & 1) ? -c12 : c12);
        S += ((__builtin_popcount(j & 0x5) & 1) ? -c13 : c13);
        S += ((__builtin_popcount(j & 0x3) & 1) ? -c23 : c23);
        S += ((j & 8) ? -Q0 : Q0);
        S += ((j & 4) ? -Q1 : Q1);
        S += ((j & 2) ? -Q2 : Q2);
        S += ((j & 1) ? -Q3 : Q3);
        float se, ce;
        __sincosf(-HPI * S, &se, &ce);
        s[j] = cmul2(u, (f2){ce, se});
    }

    // ---- layer-0 Rot gates (A = I): v = u = e_p, p = 7-k ----
    ROT0(0, 0x8, 0x0, 0x8, 0u);
    ROT0(1, 0x4, 0x0, 0x4, 0u);
    ROT0(2, 0x2, 0x0, 0x2, 0u);
    ROT0(3, 0x1, 0x0, 0x1, 0u);
    ROT0(4, 0x0, 0x8, 0x0, s8);
    ROT0(5, 0x0, 0x4, 0x0, s4);
    ROT0(6, 0x0, 0x2, 0x0, s2);
    ROT0(7, 0x0, 0x1, 0x0, s1);

    // ---- layer-0 CNOT ring folded into relabeling; RENC(k)+ROT(1,k) fused ----
    FUSED(0, 0xC, 0x0, 0x7, sF);
    FUSED(1, 0x6, 0x0, 0xC, 0u);
    FUSED(2, 0x3, 0x0, 0xE, 0u);
    FUSED(3, 0x1, 0x8, 0xF, 0u);
    FUSED(4, 0x0, 0xC, 0xF, s8);
    FUSED(5, 0x0, 0x6, 0xF, sC);
    FUSED(6, 0x0, 0x3, 0xF, sE);
    FUSED(7, 0xC, 0x1, 0xF, sF);

    // layer-1 CNOT ring folded into readout signs (final A rows, verified R2)
    // ---- readout: probs, 16-point WHT over register index, lane signs ----
    float p[16];
    #pragma unroll
    for (int j = 0; j < 16; ++j) p[j] = fmaf(s[j].y, s[j].y, s[j].x * s[j].x);
    #pragma unroll
    for (int st = 1; st < 16; st <<= 1) {
        #pragma unroll
        for (int j = 0; j < 16; ++j) {
            if ((j & st) != 0) continue;
            const float a = p[j], bb = p[j | st];
            p[j] = a + bb;  p[j | st] = a - bb;
        }
    }
    float o[8];
    o[0] = (__popc(lane16 & 0x6) & 1) ? -p[0xE] : p[0xE];
    o[1] = (__popc(lane16 & 0x3) & 1) ? -p[0xF] : p[0xF];
    o[2] = (__popc(lane16 & 0xF) & 1) ? -p[0x9] : p[0x9];
    o[3] = p[0x3];
    o[4] = (__popc(lane16 & 0x7) & 1) ? -p[0x6] : p[0x6];
    o[5] = (__popc(lane16 & 0xC) & 1) ? -p[0xC] : p[0xC];
    o[6] = (__popc(lane16 & 0x9) & 1) ? -p[0x9] : p[0x9];
    o[7] = (__popc(lane16 & 0x3) & 1) ? -p[0x3] : p[0x3];

    // cross-lane sum within the 16-lane group: all DPP now
    #pragma unroll
    for (int q = 0; q < 8; ++q) o[q] += xlane<1>(o[q]);
    #pragma unroll
    for (int q = 0; q < 8; ++q) o[q] += xlane<2>(o[q]);
    #pragma unroll
    for (int q = 0; q < 8; ++q) o[q] += xlane<4>(o[q]);
    #pragma unroll
    for (int q = 0; q < 8; ++q) o[q] += xlane<8>(o[q]);

    if (lane16 == 0 && bq < Btot) {
        float4* op = reinterpret_cast<float4*>(out + (size_t)bq * 8);
        op[0] = make_float4(o[0], o[1], o[2], o[3]);
        op[1] = make_float4(o[4], o[5], o[6], o[7]);
    }

    // ---- DIAGNOSTIC ONLY: one discarded repeat of the 16-gate core.
    // asm "+v" fences make inputs opaque (no CSE with the real pass);
    // trailing "v" sinks keep it live (no DCE, rule #17). Pushes vqc above
    // the 40us harness fills so its counters surface in top-5. Strip next.
    #pragma unroll
    for (int j = 0; j < 16; ++j) {
        float a = s[j].x, bb = s[j].y;
        asm volatile("" : "+v"(a), "+v"(bb));
        s[j].x = a; s[j].y = bb;
    }
    ROT0(0, 0x8, 0x0, 0x8, 0u);
    ROT0(1, 0x4, 0x0, 0x4, 0u);
    ROT0(2, 0x2, 0x0, 0x2, 0u);
    ROT0(3, 0x1, 0x0, 0x1, 0u);
    ROT0(4, 0x0, 0x8, 0x0, s8);
    ROT0(5, 0x0, 0x4, 0x0, s4);
    ROT0(6, 0x0, 0x2, 0x0, s2);
    ROT0(7, 0x0, 0x1, 0x0, s1);
    FUSED(0, 0xC, 0x0, 0x7, sF);
    FUSED(1, 0x6, 0x0, 0xC, 0u);
    FUSED(2, 0x3, 0x0, 0xE, 0u);
    FUSED(3, 0x1, 0x8, 0xF, 0u);
    FUSED(4, 0x0, 0xC, 0xF, s8);
    FUSED(5, 0x0, 0x6, 0xF, sC);
    FUSED(6, 0x0, 0x3, 0xF, sE);
    FUSED(7, 0xC, 0x1, 0xF, sF);
    #pragma unroll
    for (int j = 0; j < 16; ++j)
        asm volatile("" :: "v"(s[j].x), "v"(s[j].y));
}

extern "C" void kernel_launch(void* const* d_in, const int* in_sizes, int n_in,
                              void* d_out, int out_size, void* d_ws, size_t ws_size,
                              hipStream_t stream) {
    const float* theta = (const float*)d_in[0];
    const float* phi   = (const float*)d_in[1];
    const float* jup   = (const float*)d_in[2];
    const float* w     = (const float*)d_in[3];
    float* out = (float*)d_out;

    const int B = in_sizes[0] / 8;               // 16384
    const int blocks = (B * 16 + 255) / 256;     // 1024: 16 batches / block
    hipLaunchKernelGGL(vqc_kernel, dim3(blocks), dim3(256), 0, stream,
                       theta, phi, jup, w, out, B);
}

// Round 6
// 78.973 us; speedup vs baseline: 1.2539x; 1.2539x over previous
//
#include <hip/hip_runtime.h>

// TorchVQC: 8-qubit statevector, B=16384, D=256, fp32 complex.
// R13: packed-FP32 rebuild. R12 counters: VALUBusy 72%, LDS-conflict 0,
// HBM 2%, MfmaUtil 0 -> pure VALU-throughput-bound at reduced clock. Only
// lever: instruction count. gfx950 v_pk_fma_f32 = 2 FMAs/slot; LLVM lowers
// <2 x float> elementwise_fma to it (no op_sel needed — R5 lesson avoided).
// State repacked across register-index bit0: X[m]=(Re s_2m, Re s_2m+1),
// Y[m]=(Im...). 13/16 gates (VREG&1==0) run packed (64 pk-fma vs 128 fma);
// 3 gates (ROT0(3), FUSED(2), FUSED(3)) keep the verified scalar path on
// pair halves. sigma-signs from UREG = compile-time pick of pre-negated
// packed coefficient pairs (fneg folds into VOP3P neg modifiers).
// Init: S-sums packed (80 pk-add vs 160, same order -> bit-identical);
// probs packed. Diagnostic double-pass from R12 stripped.
// Layout: 4 batch elements/wave (16 lanes each), 16 amps/lane.
// Stored index s = (j<<4) | lane16. CNOTs folded via GF(2) relabeling
// (v/u tables verified R2-R4); R7 SU(2) sign-folding kept; DPP xors (R9/R12).

using f2 = __attribute__((ext_vector_type(2))) float;  // (re,im) OR packed j-pair

__device__ __forceinline__ f2 cmul2(f2 w, f2 z) {
    f2 r;
    r.x = w.x * z.x - w.y * z.y;
    r.y = w.x * z.y + w.y * z.x;
    return r;
}
__device__ __forceinline__ f2 cmadd(f2 acc, f2 w, f2 z) {
    acc.x += w.x * z.x - w.y * z.y;
    acc.y += w.x * z.y + w.y * z.x;
    return acc;
}

__device__ __forceinline__ float uxor(float f, unsigned u) {
    return __uint_as_float(__float_as_uint(f) ^ u);
}

// packed fma on f2 -> v_pk_fma_f32 (gfx90a+ packed-fp32)
__device__ __forceinline__ f2 pkfma(f2 a, f2 b, f2 c) {
    return __builtin_elementwise_fma(a, b, c);
}

template<int CTRL>
__device__ __forceinline__ int dpp1(int x) {
    return __builtin_amdgcn_update_dpp(x, x, CTRL, 0xF, 0xF, false);
}

// cross-lane value of (lane ^ M), M < 16 — ALL DPP (VALU), no LDS pipe.
template<int M>
__device__ __forceinline__ float xlane(float v) {
    const int x = __float_as_int(v);
    int r;
    if constexpr (M == 1)        r = dpp1<0xB1>(x);
    else if constexpr (M == 2)   r = dpp1<0x4E>(x);
    else if constexpr (M == 3)   r = dpp1<0x1B>(x);
    else if constexpr (M == 8)   r = dpp1<0x128>(x);
    else if constexpr (M == 0xF) r = dpp1<0x140>(x);
    else if constexpr (M == 7)   r = dpp1<0x141>(x);
    else if constexpr (M == 4)   r = dpp1<0x141>(dpp1<0x1B>(x));
    else if constexpr (M == 6)   r = dpp1<0x141>(dpp1<0xB1>(x));
    else if constexpr (M == 0xC) r = dpp1<0x140>(dpp1<0x1B>(x));
    else                         r = __builtin_amdgcn_ds_swizzle(x, (M << 10) | 0x1F);
    return __int_as_float(r);
}
template<int M>
__device__ __forceinline__ f2 xshfl2(f2 v) {
    f2 r; r.x = xlane<M>(v.x); r.y = xlane<M>(v.y); return r;
}

// broadcast lane (group8_base + K) within each group of 8 — K compile-time
template<int K>
__device__ __forceinline__ float bc8(float x) {
    return __int_as_float(__builtin_amdgcn_ds_swizzle(
        __float_as_int(x), (K << 5) | 0x18));
}
// fetch lane (lane & 0x17) | 8  (layer-1 gate params in lanes 8..15 mod 16)
#define SW117(x) __int_as_float(__builtin_amdgcn_ds_swizzle(__float_as_int(x), 0x117))

// compile-time prefetch of all 8 fused-gate coefficient quads
template<int K>
__device__ __forceinline__ void prefetchK(float (&cf0r)[8], float (&cf0i)[8],
                                          float (&cf1r)[8], float (&cf1i)[8],
                                          float F00x, float F00y,
                                          float F01x, float F01y) {
    cf0r[K] = bc8<K>(F00x); cf0i[K] = bc8<K>(F00y);
    cf1r[K] = bc8<K>(F01x); cf1i[K] = bc8<K>(F01y);
    if constexpr (K < 7)
        prefetchK<K + 1>(cf0r, cf0i, cf1r, cf1i, F00x, F00y, F01x, F01y);
}

// selected encoding-column entry: hi ? (s*cp, s*sp) : (c*cp, -c*sp)
__device__ __forceinline__ f2 enc_sel(float t, float p, bool hi) {
    float s_, c_, sp_, cp_;
    __sincosf(t * 0.5f, &s_, &c_);
    __sincosf(p * 0.5f, &sp_, &cp_);
    const float m = hi ? s_ : c_;
    f2 r; r.x = m * cp_; r.y = hi ? m * sp_ : -m * sp_;
    return r;
}

// ---- half accessors for packed state (j constant after unroll) ----
__device__ __forceinline__ float gh(const f2 (&Z)[8], int j) {
    return (j & 1) ? Z[j >> 1].y : Z[j >> 1].x;
}
__device__ __forceinline__ void sh(f2 (&Z)[8], int j, float v) {
    if (j & 1) Z[j >> 1].y = v; else Z[j >> 1].x = v;
}

// ---- packed SU(2) gate (requires VREG&1 == 0). Per half amp q, partner w:
//   x' = g00r*q.x - (sig*gi)*q.y + (sig*br)*w.x - g01i*w.y
//   y' = g00r*q.y + (sig*gi)*q.x + (sig*br)*w.y + g01i*w.x
// sig = par(q & UREG) compile-time; pair pattern from UREG bit0.
template<int VREG, int VLANE, int UREG>
__device__ __forceinline__ void gateP(f2 (&X)[8], f2 (&Y)[8],
                                      float g00r, float giS, float brS, float g01i)
{
    const f2 A  = {g00r, g00r};
    const f2 D  = {g01i, g01i}, Dn = {-g01i, -g01i};
    const float giH = (UREG & 1) ? -giS : giS;
    const float brH = (UREG & 1) ? -brS : brS;
    const f2 Gp = {giS, giH}, Gn = {-giS, -giH};
    const f2 Bp = {brS, brH}, Bn = {-brS, -brH};

    if constexpr (VREG == 0) {
        #pragma unroll
        for (int m = 0; m < 8; ++m) {
            const f2 wx = xshfl2<VLANE>(X[m]);
            const f2 wy = xshfl2<VLANE>(Y[m]);
            const f2 x = X[m], y = Y[m];
            const bool n = (__builtin_popcount((2 * m) & UREG) & 1) != 0;
            const f2 G = n ? Gn : Gp, B = n ? Bn : Bp, Gm = n ? Gp : Gn;
            X[m] = pkfma(Dn, wy, pkfma(B, wx, pkfma(Gm, y, A * x)));
            Y[m] = pkfma(D,  wx, pkfma(B, wy, pkfma(G,  x, A * y)));
        }
    } else if constexpr (VLANE == 0) {
        constexpr int VP = VREG >> 1;
        constexpr int pivot = VP & (-VP);
        #pragma unroll
        for (int m = 0; m < 8; ++m) {
            if ((m & pivot) != 0) continue;
            const int m2 = m ^ VP;
            const f2 x = X[m], y = Y[m], u = X[m2], v = Y[m2];
            const bool n1 = (__builtin_popcount((2 * m)  & UREG) & 1) != 0;
            const bool n2 = (__builtin_popcount((2 * m2) & UREG) & 1) != 0;
            const f2 G1 = n1 ? Gn : Gp, B1 = n1 ? Bn : Bp, G1m = n1 ? Gp : Gn;
            const f2 G2 = n2 ? Gn : Gp, B2 = n2 ? Bn : Bp, G2m = n2 ? Gp : Gn;
            X[m]  = pkfma(Dn, v, pkfma(B1, u, pkfma(G1m, y, A * x)));
            Y[m]  = pkfma(D,  u, pkfma(B1, v, pkfma(G1,  x, A * y)));
            X[m2] = pkfma(Dn, y, pkfma(B2, x, pkfma(G2m, v, A * u)));
            Y[m2] = pkfma(D,  x, pkfma(B2, y, pkfma(G2,  u, A * v)));
        }
    } else {
        constexpr int VP = VREG >> 1;
        constexpr int pivot = VP & (-VP);
        #pragma unroll
        for (int m = 0; m < 8; ++m) {
            if ((m & pivot) != 0) continue;
            const int m2 = m ^ VP;
            const f2 p1x = xshfl2<VLANE>(X[m2]), p1y = xshfl2<VLANE>(Y[m2]);
            const f2 p2x = xshfl2<VLANE>(X[m]),  p2y = xshfl2<VLANE>(Y[m]);
            const f2 x = X[m], y = Y[m], u = X[m2], v = Y[m2];
            const bool n1 = (__builtin_popcount((2 * m)  & UREG) & 1) != 0;
            const bool n2 = (__builtin_popcount((2 * m2) & UREG) & 1) != 0;
            const f2 G1 = n1 ? Gn : Gp, B1 = n1 ? Bn : Bp, G1m = n1 ? Gp : Gn;
            const f2 G2 = n2 ? Gn : Gp, B2 = n2 ? Bn : Bp, G2m = n2 ? Gp : Gn;
            X[m]  = pkfma(Dn, p1y, pkfma(B1, p1x, pkfma(G1m, y, A * x)));
            Y[m]  = pkfma(D,  p1x, pkfma(B1, p1y, pkfma(G1,  x, A * y)));
            X[m2] = pkfma(Dn, p2y, pkfma(B2, p2x, pkfma(G2m, v, A * u)));
            Y[m2] = pkfma(D,  p2x, pkfma(B2, p2y, pkfma(G2,  u, A * v)));
        }
    }
}

// ---- scalar gate on pair halves (the 3 gates with VREG&1 == 1) ----
template<int VREG, int VLANE, int UREG>
__device__ __forceinline__ void gateS(f2 (&X)[8], f2 (&Y)[8],
                                      float g00r, float giP, float brP, float g01i)
{
    constexpr int pivot = VREG & (-VREG);
    if constexpr (VLANE == 0) {
        #pragma unroll
        for (int j = 0; j < 16; ++j) {
            if ((j & pivot) != 0) continue;
            const int j2 = j ^ VREG;
            const float xx = gh(X, j),  xy = gh(Y, j);
            const float yx = gh(X, j2), yy = gh(Y, j2);
            {
                const bool n = (__builtin_popcount(j & UREG) & 1) != 0;
                const float gi = n ? -giP : giP, br = n ? -brP : brP;
                sh(X, j, fmaf(-g01i, yy, fmaf(br, yx, fmaf(-gi, xy, g00r * xx))));
                sh(Y, j, fmaf( g01i, yx, fmaf(br, yy, fmaf( gi, xx, g00r * xy))));
            }
            {
                const bool n = (__builtin_popcount(j2 & UREG) & 1) != 0;
                const float gi = n ? -giP : giP, br = n ? -brP : brP;
                sh(X, j2, fmaf(-g01i, xy, fmaf(br, xx, fmaf(-gi, yy, g00r * yx))));
                sh(Y, j2, fmaf( g01i, xx, fmaf(br, xy, fmaf( gi, yx, g00r * yy))));
            }
        }
    } else {
        #pragma unroll
        for (int j = 0; j < 16; ++j) {
            if ((j & pivot) != 0) continue;
            const int j2 = j ^ VREG;
            const float p1x = xlane<VLANE>(gh(X, j2)), p1y = xlane<VLANE>(gh(Y, j2));
            const float p2x = xlane<VLANE>(gh(X, j)),  p2y = xlane<VLANE>(gh(Y, j));
            const float xx = gh(X, j),  xy = gh(Y, j);
            const float yx = gh(X, j2), yy = gh(Y, j2);
            {
                const bool n = (__builtin_popcount(j & UREG) & 1) != 0;
                const float gi = n ? -giP : giP, br = n ? -brP : brP;
                sh(X, j, fmaf(-g01i, p1y, fmaf(br, p1x, fmaf(-gi, xy, g00r * xx))));
                sh(Y, j, fmaf( g01i, p1x, fmaf(br, p1y, fmaf( gi, xx, g00r * xy))));
            }
            {
                const bool n = (__builtin_popcount(j2 & UREG) & 1) != 0;
                const float gi = n ? -giP : giP, br = n ? -brP : brP;
                sh(X, j2, fmaf(-g01i, p2y, fmaf(br, p2x, fmaf(-gi, yy, g00r * yx))));
                sh(Y, j2, fmaf( g01i, p2x, fmaf(br, p2y, fmaf( gi, yx, g00r * yy))));
            }
        }
    }
}

// uniform broadcast from wave lane t (compile-time) -> SGPR
#define RL(x, t) __int_as_float(__builtin_amdgcn_readlane(__float_as_int(x), (t)))

// layer-0 Rot: coefficients wave-uniform from lane K's w-gate regs
#define ROT0P(K, VR, VL, UR, SL)                                            \
    gateP<VR, VL, UR>(X, Y, RL(q00r, K), uxor(RL(q00i, K), SL),             \
                      uxor(RL(q01r, K), SL), RL(q01i, K))
#define ROT0S(K, VR, VL, UR, SL)                                            \
    gateS<VR, VL, UR>(X, Y, RL(q00r, K), uxor(RL(q00i, K), SL),             \
                      uxor(RL(q01r, K), SL), RL(q01i, K))
// fused Renc(K)+Rot(1,K): coefficients prefetched long ago
#define FUSEDP(K, VR, VL, UR, SL)                                           \
    gateP<VR, VL, UR>(X, Y, cf0r[K], uxor(cf0i[K], SL),                     \
                      uxor(cf1r[K], SL), cf1i[K])
#define FUSEDS(K, VR, VL, UR, SL)                                           \
    gateS<VR, VL, UR>(X, Y, cf0r[K], uxor(cf0i[K], SL),                     \
                      uxor(cf1r[K], SL), cf1i[K])

__global__ __launch_bounds__(256, 4) void vqc_kernel(
    const float* __restrict__ theta,   // [B,8]
    const float* __restrict__ phi,     // [B,8]
    const float* __restrict__ jup,     // [B,28]
    const float* __restrict__ w,       // [2,8,3] vqc weights
    float* __restrict__ out,           // [B,8]
    int Btot)
{
    const int gtid   = blockIdx.x * 256 + threadIdx.x;
    const int lane   = threadIdx.x & 63;
    const int lane16 = lane & 15;
    const int bq     = gtid >> 4;                   // one batch per 16 lanes
    const int b      = bq < Btot ? bq : Btot - 1;   // clamp for loads

    // ---- w-gate prep (lane t holds gate t=lane&15) ----
    float q00r, q00i, q01r, q01i;
    {
        const int gt = lane & 15;
        const float wph = w[gt*3+0], wth = w[gt*3+1], wom = w[gt*3+2];
        float gc_, gs_, ca_, sa_, cb_, sb_;
        __sincosf(wth * 0.5f, &gs_, &gc_);
        __sincosf(0.5f * (wph + wom), &sa_, &ca_);
        __sincosf(0.5f * (wph - wom), &sb_, &cb_);
        q00r =  gc_*ca_;  q00i = -gc_*sa_;
        q01r = -gs_*cb_;  q01i = -gs_*sb_;
    }

    const int Kq = lane & 7;
    const float thK = theta[(size_t)b * 8 + Kq];
    const float phK = phi  [(size_t)b * 8 + Kq];

    float th[8], ph[8];
    {
        const float4* t4 = reinterpret_cast<const float4*>(theta + (size_t)b * 8);
        const float4* p4 = reinterpret_cast<const float4*>(phi   + (size_t)b * 8);
        const float4 a = t4[0], c = t4[1], d = p4[0], e = p4[1];
        th[0]=a.x; th[1]=a.y; th[2]=a.z; th[3]=a.w;
        th[4]=c.x; th[5]=c.y; th[6]=c.z; th[7]=c.w;
        ph[0]=d.x; ph[1]=d.y; ph[2]=d.z; ph[3]=d.w;
        ph[4]=e.x; ph[5]=e.y; ph[6]=e.z; ph[7]=e.w;
    }

    // ---- distributed FUSED-gate build (R8-verified math) ----
    float F00x, F00y, F01x, F01y;
    {
        float c_, s_, cp_, sp_;
        __sincosf(thK * 0.25f, &s_, &c_);
        __sincosf(phK * 0.25f, &sp_, &cp_);
        const f2 R00 = { SW117(q00r), SW117(q00i) };
        const f2 R01 = { SW117(q01r), SW117(q01i) };
        const f2 E00 = { c_*cp_, -c_*sp_}, E10 = { s_*cp_,  s_*sp_};
        const f2 E01 = {-s_*cp_,  s_*sp_}, E11 = { c_*cp_,  c_*sp_};
        const f2 F00 = cmadd(cmul2(R00, E00), R01, E10);
        const f2 F01 = cmadd(cmul2(R00, E01), R01, E11);
        F00x = F00.x; F00y = F00.y; F01x = F01.x; F01y = F01.y;
    }

    // ---- prefetch fused-gate coefficients (32 ds_swizzle, consumed late) ----
    float cf0r[8], cf0i[8], cf1r[8], cf1i[8];
    prefetchK<0>(cf0r, cf0i, cf1r, cf1i, F00x, F00y, F01x, F01y);

    // lane-parity sign words (bit31)
    const unsigned s8 = (unsigned)(lane16 & 8) << 28;
    const unsigned s4 = (unsigned)(lane16 & 4) << 29;
    const unsigned s2 = (unsigned)(lane16 & 2) << 30;
    const unsigned s1 = (unsigned)(lane16 & 1) << 31;
    const unsigned sC = s8 ^ s4;
    const unsigned sE = sC ^ s2;
    const unsigned sF = sE ^ s1;

    // ---- lane-side encoding product over qubits 4..7 ----
    f2 P = enc_sel(th[4], ph[4], (lane16 & 8) != 0);
    P = cmul2(P, enc_sel(th[5], ph[5], (lane16 & 4) != 0));
    P = cmul2(P, enc_sel(th[6], ph[6], (lane16 & 2) != 0));
    P = cmul2(P, enc_sel(th[7], ph[7], (lane16 & 1) != 0));

    // ---- register-side partial products ----
    f2 m01[4], m23[4];
    {
        float s0, c0, sp0, cp0, s1_, c1_, sp1, cp1;
        __sincosf(th[0]*0.5f, &s0, &c0); __sincosf(ph[0]*0.5f, &sp0, &cp0);
        __sincosf(th[1]*0.5f, &s1_, &c1_); __sincosf(ph[1]*0.5f, &sp1, &cp1);
        const f2 A0={c0*cp0,-c0*sp0}, A1={s0*cp0,s0*sp0};
        const f2 B0={c1_*cp1,-c1_*sp1}, B1={s1_*cp1,s1_*sp1};
        #pragma unroll
        for (int a = 0; a < 4; ++a)
            m01[a] = cmul2((a & 2) ? A1 : A0, (a & 1) ? B1 : B0);
        __sincosf(th[2]*0.5f, &s0, &c0); __sincosf(ph[2]*0.5f, &sp0, &cp0);
        __sincosf(th[3]*0.5f, &s1_, &c1_); __sincosf(ph[3]*0.5f, &sp1, &cp1);
        const f2 C0={c0*cp0,-c0*sp0}, C1={s0*cp0,s0*sp0};
        const f2 D0={c1_*cp1,-c1_*sp1}, D1={s1_*cp1,s1_*sp1};
        #pragma unroll
        for (int a = 0; a < 4; ++a)
            m23[a] = cmul2((a & 2) ? C1 : C0, (a & 1) ? D1 : D0);
    }

    // ---- IsingZZ reduction ----
    float c01, c02, c03, c12, c13, c23, Q0, Q1, Q2, Q3, LL;
    {
        const float4* J4 = reinterpret_cast<const float4*>(jup + (size_t)b * 28);
        const float z4 = (lane16 & 8) ? -1.f : 1.f;
        const float z5 = (lane16 & 4) ? -1.f : 1.f;
        const float z6 = (lane16 & 2) ? -1.f : 1.f;
        const float z7 = (lane16 & 1) ? -1.f : 1.f;
        const float4 x0 = J4[0], x1 = J4[1], x2 = J4[2], x3 = J4[3];
        const float4 x4 = J4[4], x5 = J4[5], x6 = J4[6];
        c01 = x0.x; c02 = x0.y; c03 = x0.z;
        Q0  = x0.w*z4 + x1.x*z5 + x1.y*z6 + x1.z*z7;
        c12 = x1.w; c13 = x2.x;
        Q1  = x2.y*z4 + x2.z*z5 + x2.w*z6 + x3.x*z7;
        c23 = x3.y;
        Q2  = x3.z*z4 + x3.w*z5 + x4.x*z6 + x4.y*z7;
        Q3  = x4.z*z4 + x4.w*z5 + x5.x*z6 + x5.y*z7;
        LL  = x5.z*(z4*z5) + x5.w*(z4*z6) + x6.x*(z4*z7)
            + x6.y*(z5*z6) + x6.z*(z5*z7) + x6.w*(z6*z7);
    }

    // ---- packed S per amplitude pair (same add order as scalar R7) ----
    f2 Spk[8];
    {
        const f2 Tc01 = {c01,  c01};   // mask 0xC
        const f2 Tc02 = {c02,  c02};   // 0xA
        const f2 Tc03 = {c03, -c03};   // 0x9 (bit0)
        const f2 Tc12 = {c12,  c12};   // 0x6
        const f2 Tc13 = {c13, -c13};   // 0x5 (bit0)
        const f2 Tc23 = {c23, -c23};   // 0x3 (bit0)
        const f2 TQ0  = {Q0,   Q0};    // 0x8
        const f2 TQ1  = {Q1,   Q1};    // 0x4
        const f2 TQ2  = {Q2,   Q2};    // 0x2
        const f2 TQ3  = {Q3,  -Q3};    // 0x1 (bit0)
        const f2 LLp  = {LL,   LL};
        #pragma unroll
        for (int m = 0; m < 8; ++m) {
            const int j = 2 * m;
            f2 S = LLp;
            S += ((__builtin_popcount(j & 0xC) & 1) ? -Tc01 : Tc01);
            S += ((__builtin_popcount(j & 0xA) & 1) ? -Tc02 : Tc02);
            S += ((__builtin_popcount(j & 0x9) & 1) ? -Tc03 : Tc03);
            S += ((__builtin_popcount(j & 0x6) & 1) ? -Tc12 : Tc12);
            S += ((__builtin_popcount(j & 0x5) & 1) ? -Tc13 : Tc13);
            S += ((__builtin_popcount(j & 0x3) & 1) ? -Tc23 : Tc23);
            S += ((j & 8) ? -TQ0 : TQ0);
            S += ((j & 4) ? -TQ1 : TQ1);
            S += ((j & 2) ? -TQ2 : TQ2);
            S += ((j & 1) ? -TQ3 : TQ3);
            Spk[m] = S;
        }
    }

    // ---- init amplitudes into packed state X/Y ----
    f2 X[8], Y[8];
    constexpr float HPI = 1.5707963267948966f;
    #pragma unroll
    for (int j = 0; j < 16; ++j) {
        const f2 u = cmul2(cmul2(m01[j >> 2], m23[j & 3]), P);
        const float Sv = (j & 1) ? Spk[j >> 1].y : Spk[j >> 1].x;
        float se, ce;
        __sincosf(-HPI * Sv, &se, &ce);
        const f2 sj = cmul2(u, (f2){ce, se});
        sh(X, j, sj.x);
        sh(Y, j, sj.y);
    }

    // ---- layer-0 Rot gates (A = I): v = u = e_p, p = 7-k ----
    ROT0P(0, 0x8, 0x0, 0x8, 0u);
    ROT0P(1, 0x4, 0x0, 0x4, 0u);
    ROT0P(2, 0x2, 0x0, 0x2, 0u);
    ROT0S(3, 0x1, 0x0, 0x1, 0u);
    ROT0P(4, 0x0, 0x8, 0x0, s8);
    ROT0P(5, 0x0, 0x4, 0x0, s4);
    ROT0P(6, 0x0, 0x2, 0x0, s2);
    ROT0P(7, 0x0, 0x1, 0x0, s1);

    // ---- layer-0 CNOT ring folded; RENC(k)+ROT(1,k) fused ----
    FUSEDP(0, 0xC, 0x0, 0x7, sF);
    FUSEDP(1, 0x6, 0x0, 0xC, 0u);
    FUSEDS(2, 0x3, 0x0, 0xE, 0u);
    FUSEDS(3, 0x1, 0x8, 0xF, 0u);
    FUSEDP(4, 0x0, 0xC, 0xF, s8);
    FUSEDP(5, 0x0, 0x6, 0xF, sC);
    FUSEDP(6, 0x0, 0x3, 0xF, sE);
    FUSEDP(7, 0xC, 0x1, 0xF, sF);

    // ---- readout: packed probs, scalar 16-pt WHT, lane signs ----
    float p[16];
    #pragma unroll
    for (int m = 0; m < 8; ++m) {
        const f2 pp = pkfma(Y[m], Y[m], X[m] * X[m]);
        p[2*m] = pp.x; p[2*m+1] = pp.y;
    }
    #pragma unroll
    for (int st = 1; st < 16; st <<= 1) {
        #pragma unroll
        for (int j = 0; j < 16; ++j) {
            if ((j & st) != 0) continue;
            const float a = p[j], bb = p[j | st];
            p[j] = a + bb;  p[j | st] = a - bb;
        }
    }
    float o[8];
    o[0] = (__popc(lane16 & 0x6) & 1) ? -p[0xE] : p[0xE];
    o[1] = (__popc(lane16 & 0x3) & 1) ? -p[0xF] : p[0xF];
    o[2] = (__popc(lane16 & 0xF) & 1) ? -p[0x9] : p[0x9];
    o[3] = p[0x3];
    o[4] = (__popc(lane16 & 0x7) & 1) ? -p[0x6] : p[0x6];
    o[5] = (__popc(lane16 & 0xC) & 1) ? -p[0xC] : p[0xC];
    o[6] = (__popc(lane16 & 0x9) & 1) ? -p[0x9] : p[0x9];
    o[7] = (__popc(lane16 & 0x3) & 1) ? -p[0x3] : p[0x3];

    // cross-lane sum within the 16-lane group: all DPP
    #pragma unroll
    for (int q = 0; q < 8; ++q) o[q] += xlane<1>(o[q]);
    #pragma unroll
    for (int q = 0; q < 8; ++q) o[q] += xlane<2>(o[q]);
    #pragma unroll
    for (int q = 0; q < 8; ++q) o[q] += xlane<4>(o[q]);
    #pragma unroll
    for (int q = 0; q < 8; ++q) o[q] += xlane<8>(o[q]);

    if (lane16 == 0 && bq < Btot) {
        float4* op = reinterpret_cast<float4*>(out + (size_t)bq * 8);
        op[0] = make_float4(o[0], o[1], o[2], o[3]);
        op[1] = make_float4(o[4], o[5], o[6], o[7]);
    }
}

extern "C" void kernel_launch(void* const* d_in, const int* in_sizes, int n_in,
                              void* d_out, int out_size, void* d_ws, size_t ws_size,
                              hipStream_t stream) {
    const float* theta = (const float*)d_in[0];
    const float* phi   = (const float*)d_in[1];
    const float* jup   = (const float*)d_in[2];
    const float* w     = (const float*)d_in[3];
    float* out = (float*)d_out;

    const int B = in_sizes[0] / 8;               // 16384
    const int blocks = (B * 16 + 255) / 256;     // 1024: 16 batches / block
    hipLaunchKernelGGL(vqc_kernel, dim3(blocks), dim3(256), 0, stream,
                       theta, phi, jup, w, out, B);
}